// Round 3
// baseline (2119.223 us; speedup 1.0000x reference)
//
#include <hip/hip_runtime.h>
#include <math.h>

#define DIM_K 7168
#define NE 256
#define NG 8
#define GSZ 32
#define TOPKN 8
#define TOPKG 4

constexpr int BM = 32;   // tokens per block
constexpr int BK = 16;   // k-chunk

// ---------------------------------------------------------------------------
// Scores: f64-accumulated logits (error ~1e-13, far below f32 ulp), f64
// sigmoid, then ROUND TO F32 — hypothesis: the np reference stores scores as
// float32 and routes in f32. The f32 rounding is the semantic step round 2
// was missing; everything upstream just needs to be << f32-ulp accurate.
// ---------------------------------------------------------------------------
__global__ __launch_bounds__(256, 2)
void gemm_sigmoid_f64_q32(const float* __restrict__ x,
                          const float* __restrict__ w,
                          float* __restrict__ scores)
{
    __shared__ float As[BK][BM];   // As[k][m]
    __shared__ float Bs[BK][NE];   // Bs[k][e]

    const int tid = threadIdx.x;
    const int m_blk = blockIdx.x * BM;

    const int e0 = (tid & 63) * 4;
    const int m0 = (tid >> 6) * 8;

    double acc[8][4];
#pragma unroll
    for (int i = 0; i < 8; ++i)
#pragma unroll
        for (int j = 0; j < 4; ++j) acc[i][j] = 0.0;

    const int arow = tid >> 2;
    const int ac4  = tid & 3;

    for (int k0 = 0; k0 < DIM_K; k0 += BK) {
        if (tid < 128) {
            const float4 av = *(const float4*)(x + (long)(m_blk + arow) * DIM_K + k0 + ac4 * 4);
            As[ac4 * 4 + 0][arow] = av.x;
            As[ac4 * 4 + 1][arow] = av.y;
            As[ac4 * 4 + 2][arow] = av.z;
            As[ac4 * 4 + 3][arow] = av.w;
        }
#pragma unroll
        for (int l = 0; l < 4; ++l) {
            const int e = (tid >> 2) + 64 * l;
            const float4 bv = *(const float4*)(w + (long)e * DIM_K + k0 + ac4 * 4);
            Bs[ac4 * 4 + 0][e] = bv.x;
            Bs[ac4 * 4 + 1][e] = bv.y;
            Bs[ac4 * 4 + 2][e] = bv.z;
            Bs[ac4 * 4 + 3][e] = bv.w;
        }
        __syncthreads();
#pragma unroll
        for (int k = 0; k < BK; ++k) {
            const float4 a0 = *(const float4*)&As[k][m0];
            const float4 a1 = *(const float4*)&As[k][m0 + 4];
            const float4 b  = *(const float4*)&Bs[k][e0];
            const double av[8] = {(double)a0.x, (double)a0.y, (double)a0.z, (double)a0.w,
                                  (double)a1.x, (double)a1.y, (double)a1.z, (double)a1.w};
            const double bv[4] = {(double)b.x, (double)b.y, (double)b.z, (double)b.w};
#pragma unroll
            for (int i = 0; i < 8; ++i)
#pragma unroll
                for (int j = 0; j < 4; ++j)
                    acc[i][j] = fma(av[i], bv[j], acc[i][j]);
        }
        __syncthreads();
    }

#pragma unroll
    for (int i = 0; i < 8; ++i) {
        float4 o;   // f64 sigmoid, RNE cast to f32 == np .astype(float32)
        o.x = (float)(1.0 / (1.0 + exp(-acc[i][0])));
        o.y = (float)(1.0 / (1.0 + exp(-acc[i][1])));
        o.z = (float)(1.0 / (1.0 + exp(-acc[i][2])));
        o.w = (float)(1.0 / (1.0 + exp(-acc[i][3])));
        *(float4*)(scores + (long)(m_blk + m0 + i) * NE + e0) = o;
    }
}

// np-faithful f32 routing. All comparisons on f32(score)+f32(bias) computed
// with a single f32 RNE add (bit-identical every rescan). Strict '>' scans =
// jax.lax.top_k semantics (descending, lowest index on ties, stable).
__global__ __launch_bounds__(64)
void route_f32(const float* __restrict__ scores,
               const float* __restrict__ bias,
               float* __restrict__ out_w,
               float* __restrict__ out_i)
{
    __shared__ float srow[64][NE + 1];
    __shared__ float bsh[NE];

    const int tid = threadIdx.x;
    const long tok0 = (long)blockIdx.x * 64;

#pragma unroll
    for (int l = 0; l < 4; ++l) bsh[tid * 4 + l] = bias[tid * 4 + l];

    for (int l = 0; l < 64; ++l) {
        const float4 v = *(const float4*)(scores + (tok0 + l) * NE + tid * 4);
        srow[l][tid * 4 + 0] = v.x;
        srow[l][tid * 4 + 1] = v.y;
        srow[l][tid * 4 + 2] = v.z;
        srow[l][tid * 4 + 3] = v.w;
    }
    __syncthreads();

    float* row = srow[tid];

    // group score = top-2 sum of biased scores (f32 add, m1+m2 order = np)
    float gs[NG];
#pragma unroll
    for (int g = 0; g < NG; ++g) {
        float m1 = -3.0e38f, m2 = -3.0e38f;
        for (int j = 0; j < GSZ; ++j) {
            const int e = g * GSZ + j;
            const float v = __fadd_rn(row[e], bsh[e]);
            if (v > m1) { m2 = m1; m1 = v; }
            else if (v > m2) { m2 = v; }
        }
        gs[g] = __fadd_rn(m1, m2);
    }

    // top-4 groups (selection set only)
    unsigned keep = 0;
#pragma unroll
    for (int r = 0; r < TOPKG; ++r) {
        float best = -3.0e38f; int bg = 0;
        for (int g = 0; g < NG; ++g)
            if (!((keep >> g) & 1u) && gs[g] > best) { best = gs[g]; bg = g; }
        keep |= 1u << bg;
    }

    // top-8 experts over kept groups by biased f32 score
    float wv[TOPKN]; int iv[TOPKN];
    for (int r = 0; r < TOPKN; ++r) {
        float best = -3.0e38f; int bi = 0;
        for (int g = 0; g < NG; ++g) {
            if (!((keep >> g) & 1u)) continue;
            for (int j = 0; j < GSZ; ++j) {
                const int e = g * GSZ + j;
                const float v = __fadd_rn(row[e], bsh[e]);
                if (v > best) { best = v; bi = e; }
            }
        }
        wv[r] = row[bi];        // ORIGINAL (un-biased) f32 sigmoid score
        iv[r] = bi;
        row[bi] = -3.0e38f;     // -3e38 + bias stays -3e38; never re-picked
    }

    // np n=8 pairwise-sum tree, then div-then-mul (elementwise, f32)
    const float s01 = __fadd_rn(wv[0], wv[1]);
    const float s23 = __fadd_rn(wv[2], wv[3]);
    const float s45 = __fadd_rn(wv[4], wv[5]);
    const float s67 = __fadd_rn(wv[6], wv[7]);
    const float wsum = __fadd_rn(__fadd_rn(s01, s23), __fadd_rn(s45, s67));

    const long token = tok0 + tid;
#pragma unroll
    for (int r = 0; r < TOPKN; ++r) {
        out_w[token * 8 + r] = __fmul_rn(__fdiv_rn(wv[r], wsum), 2.5f);
        out_i[token * 8 + r] = (float)iv[r];
    }
}

extern "C" void kernel_launch(void* const* d_in, const int* in_sizes, int n_in,
                              void* d_out, int out_size, void* d_ws, size_t ws_size,
                              hipStream_t stream)
{
    const float* x    = (const float*)d_in[0];
    const float* w    = (const float*)d_in[1];
    const float* bias = (const float*)d_in[2];
    float* out = (float*)d_out;
    const int T = in_sizes[0] / DIM_K;      // 16384
    float* scores = (float*)d_ws;           // T*256 f32 = 16.8 MB

    gemm_sigmoid_f64_q32<<<dim3(T / BM), dim3(256), 0, stream>>>(x, w, scores);
    route_f32<<<dim3(T / 64), dim3(64), 0, stream>>>(scores, bias, out,
                                                     out + (long)T * TOPKN);
}